// Round 2
// baseline (83.580 us; speedup 1.0000x reference)
//
#include <hip/hip_runtime.h>

#define GAMMA 0.1f

constexpr int MTOT = 65536;
constexpr int NTOT = 1024;
constexpr int KDIM = 64;

using frag_ab = __attribute__((ext_vector_type(8))) short;  // 8 bf16 (4 VGPRs)
using f32x4   = __attribute__((ext_vector_type(4))) float;  // 4 f32 acc

typedef __attribute__((address_space(1))) const unsigned int gu32;
typedef __attribute__((address_space(3))) unsigned int lu32;

// ---------------- workspace layout (bytes) ----------------
constexpr size_t WS_XHI = 0;                       // 65536*64*2 = 8388608
constexpr size_t WS_XLO = WS_XHI + 8388608;
constexpr size_t WS_CHI = WS_XLO + 8388608;        // 1024*64*2 = 131072
constexpr size_t WS_CLO = WS_CHI + 131072;
constexpr size_t WS_XSQ = WS_CLO + 131072;         // 65536*4 = 262144
constexpr size_t WS_CSQ = WS_XSQ + 262144;         // 1024*4 = 4096
constexpr size_t WS_NEEDED = WS_CSQ + 4096;        // 17,305,600 B

// f32 -> bf16 round-to-nearest-even; 'back' is the rounded value as f32.
__device__ __forceinline__ ushort bf16_rne(float x, float& back) {
  unsigned u = __float_as_uint(x);
  unsigned r = (u + 0x7FFFu + ((u >> 16) & 1u)) >> 16;
  back = __uint_as_float(r << 16);
  return (ushort)r;
}

// ================= kernel 1: f32 rows -> bf16 hi/lo (pre-swizzled) + row norms =================
__global__ __launch_bounds__(256)
void rbf_convert_kernel(const float* __restrict__ src,
                        ushort* __restrict__ hi, ushort* __restrict__ lo,
                        float* __restrict__ sq) {
  const int c = blockIdx.x * 256 + threadIdx.x;   // global 16B-chunk id
  const int row = c >> 3;
  const int s = c & 7;
  const float4* p = reinterpret_cast<const float4*>(src + (size_t)row * KDIM + s * 8);
  float4 v0 = p[0];
  float4 v1 = p[1];
  float v[8] = {v0.x, v0.y, v0.z, v0.w, v1.x, v1.y, v1.z, v1.w};
  frag_ab hv, lv;
  float ss = 0.0f;
  #pragma unroll
  for (int i = 0; i < 8; ++i) {
    float back;
    ushort hb = bf16_rne(v[i], back);
    float b2;
    ushort lb = bf16_rne(v[i] - back, b2);
    (void)b2;
    ss += v[i] * v[i];
    hv[i] = (short)hb;
    lv[i] = (short)lb;
  }
  ss += __shfl_xor(ss, 1);
  ss += __shfl_xor(ss, 2);
  ss += __shfl_xor(ss, 4);
  if (s == 0) sq[row] = ss;
  const int slot = s ^ (row & 7);   // bake the LDS bank swizzle into the global layout
  *reinterpret_cast<frag_ab*>(hi + (size_t)row * KDIM + slot * 8) = hv;
  *reinterpret_cast<frag_ab*>(lo + (size_t)row * KDIM + slot * 8) = lv;
}

// ================= kernel 2: MFMA GEMM + RBF epilogue =================
// Tile: 64 x-rows (m) x 128 centers (n). A-role = centers, B-role = x, so D's
// reg-varying dim is n -> float4 output stores. LDS 48 KB -> 3 blocks/CU.
__global__ __launch_bounds__(256, 3)
void rbf_gemm_kernel(const ushort* __restrict__ xhi, const ushort* __restrict__ xlo,
                     const ushort* __restrict__ chi, const ushort* __restrict__ clo,
                     const float* __restrict__ xsq, const float* __restrict__ csq,
                     float* __restrict__ out) {
  // LDS image (16B chunks): [chi 16KB][clo 16KB][xhi 8KB][xlo 8KB] = 48 KB
  __shared__ ushort smem[24576];
  ushort* sChi = smem;           // 128 rows x 64
  ushort* sClo = smem + 8192;
  ushort* sXhi = smem + 16384;   // 64 rows x 64
  ushort* sXlo = smem + 20480;

  const int tid = threadIdx.x;
  const int mt = blockIdx.x >> 3;   // 1024 m-tiles (64 rows each)
  const int nt = blockIdx.x & 7;    // 8 n-tiles (128 centers each)

  // ---- stage 48 KB via global_load_lds width-16: 12 chunks/thread, linear LDS dest ----
  const char* chiT = reinterpret_cast<const char*>(chi) + (size_t)nt * 16384;
  const char* cloT = reinterpret_cast<const char*>(clo) + (size_t)nt * 16384;
  const char* xhiT = reinterpret_cast<const char*>(xhi) + (size_t)mt * 8192;
  const char* xloT = reinterpret_cast<const char*>(xlo) + (size_t)mt * 8192;
  char* lbase = reinterpret_cast<char*>(smem);
  #pragma unroll
  for (int p = 0; p < 12; ++p) {
    const int c = p * 256 + tid;   // 16B chunk id within LDS image
    const char* g;
    if (p < 4)       g = chiT + (size_t)c * 16;
    else if (p < 8)  g = cloT + (size_t)(c - 1024) * 16;
    else if (p < 10) g = xhiT + (size_t)(c - 2048) * 16;
    else             g = xloT + (size_t)(c - 2560) * 16;
    __builtin_amdgcn_global_load_lds((gu32*)g, (lu32*)(lbase + (size_t)c * 16), 16, 0, 0);
  }
  __syncthreads();   // drains vmcnt before any LDS read

  const int lane = tid & 63;
  const int wave = tid >> 6;
  const int wn = wave >> 1;        // n-half: 0..1 (64 centers each)
  const int wm = wave & 1;         // m-half: 0..1 (32 x-rows each)
  const int r16 = lane & 15;
  const int g = lane >> 4;         // k-group 0..3

  f32x4 acc[4][2] = {};            // [nFrag][mFrag]

  #pragma unroll
  for (int ks = 0; ks < 2; ++ks) {
    const int slot = (ks * 4 + g) ^ (r16 & 7);   // rows are multiples of 16 -> row&7 == r16&7
    frag_ab ch[4], cl[4], xh[2], xl[2];
    #pragma unroll
    for (int nf = 0; nf < 4; ++nf) {
      const int row = wn * 64 + nf * 16 + r16;
      ch[nf] = *reinterpret_cast<const frag_ab*>(sChi + row * 64 + slot * 8);
      cl[nf] = *reinterpret_cast<const frag_ab*>(sClo + row * 64 + slot * 8);
    }
    #pragma unroll
    for (int mf = 0; mf < 2; ++mf) {
      const int row = wm * 32 + mf * 16 + r16;
      xh[mf] = *reinterpret_cast<const frag_ab*>(sXhi + row * 64 + slot * 8);
      xl[mf] = *reinterpret_cast<const frag_ab*>(sXlo + row * 64 + slot * 8);
    }
    #pragma unroll
    for (int nf = 0; nf < 4; ++nf) {
      #pragma unroll
      for (int mf = 0; mf < 2; ++mf) {
        // cross = ch*xh + ch*xl + cl*xh (lo*lo dropped, ~1e-6)
        acc[nf][mf] = __builtin_amdgcn_mfma_f32_16x16x32_bf16(ch[nf], xh[mf], acc[nf][mf], 0, 0, 0);
        acc[nf][mf] = __builtin_amdgcn_mfma_f32_16x16x32_bf16(ch[nf], xl[mf], acc[nf][mf], 0, 0, 0);
        acc[nf][mf] = __builtin_amdgcn_mfma_f32_16x16x32_bf16(cl[nf], xh[mf], acc[nf][mf], 0, 0, 0);
      }
    }
  }

  // ---- epilogue: out[m][n] = exp(-g*max(xsq+csq-2*cross,0)), float4 along n ----
  const size_t m0g = (size_t)mt * 64 + wm * 32;   // + mf*16 + r16
  const int n0g = nt * 128 + wn * 64;             // + nf*16 + g*4

  float xs[2];
  #pragma unroll
  for (int mf = 0; mf < 2; ++mf) xs[mf] = xsq[m0g + mf * 16 + r16];

  #pragma unroll
  for (int nf = 0; nf < 4; ++nf) {
    const float4 cs = *reinterpret_cast<const float4*>(csq + n0g + nf * 16 + g * 4);
    #pragma unroll
    for (int mf = 0; mf < 2; ++mf) {
      const f32x4 a = acc[nf][mf];
      float4 o;
      o.x = __expf(-GAMMA * fmaxf(xs[mf] + cs.x - 2.0f * a[0], 0.0f));
      o.y = __expf(-GAMMA * fmaxf(xs[mf] + cs.y - 2.0f * a[1], 0.0f));
      o.z = __expf(-GAMMA * fmaxf(xs[mf] + cs.z - 2.0f * a[2], 0.0f));
      o.w = __expf(-GAMMA * fmaxf(xs[mf] + cs.w - 2.0f * a[3], 0.0f));
      *reinterpret_cast<float4*>(out + (m0g + mf * 16 + r16) * (size_t)NTOT + n0g + nf * 16 + g * 4) = o;
    }
  }
}

// ================= fallback: round-1 single kernel (known-good) =================
__device__ __forceinline__ void stage_tile_fb(const float* __restrict__ src,
                                              ushort* hi, ushort* lo, float* sq,
                                              int tid) {
  #pragma unroll
  for (int pass = 0; pass < 4; ++pass) {
    const int idx = pass * 2048 + tid * 8;
    const int row = idx >> 6;
    const int s = tid & 7;
    const float4* p = reinterpret_cast<const float4*>(src + idx);
    float4 v0 = p[0];
    float4 v1 = p[1];
    float v[8] = {v0.x, v0.y, v0.z, v0.w, v1.x, v1.y, v1.z, v1.w};
    frag_ab hv, lv;
    float ss = 0.0f;
    #pragma unroll
    for (int i = 0; i < 8; ++i) {
      float back;
      ushort hb = bf16_rne(v[i], back);
      float b2;
      ushort lb = bf16_rne(v[i] - back, b2);
      (void)b2;
      ss += v[i] * v[i];
      hv[i] = (short)hb;
      lv[i] = (short)lb;
    }
    ss += __shfl_xor(ss, 1);
    ss += __shfl_xor(ss, 2);
    ss += __shfl_xor(ss, 4);
    if (s == 0) sq[row] = ss;
    const int slot = s ^ (row & 7);
    *reinterpret_cast<frag_ab*>(hi + row * 64 + slot * 8) = hv;
    *reinterpret_cast<frag_ab*>(lo + row * 64 + slot * 8) = lv;
  }
}

__global__ __launch_bounds__(256, 2)
void rbf_fallback_kernel(const float* __restrict__ x,
                         const float* __restrict__ centers,
                         float* __restrict__ out) {
  __shared__ ushort sAhi[128 * 64];
  __shared__ ushort sAlo[128 * 64];
  __shared__ ushort sBhi[128 * 64];
  __shared__ ushort sBlo[128 * 64];
  __shared__ float sAsq[128];
  __shared__ float sBsq[128];

  const int tid = threadIdx.x;
  const int mt = blockIdx.x >> 3;
  const int nt = blockIdx.x & 7;

  stage_tile_fb(x + (size_t)mt * 128 * KDIM, sAhi, sAlo, sAsq, tid);
  stage_tile_fb(centers + (size_t)nt * 128 * KDIM, sBhi, sBlo, sBsq, tid);
  __syncthreads();

  const int lane = tid & 63;
  const int wave = tid >> 6;
  const int wr = wave >> 1;
  const int wc = wave & 1;
  const int r16 = lane & 15;
  const int g = lane >> 4;

  f32x4 acc[4][4] = {};

  #pragma unroll
  for (int ks = 0; ks < 2; ++ks) {
    const int slot = (ks * 4 + g) ^ (r16 & 7);
    frag_ab ah[4], al[4], bh[4], bl[4];
    #pragma unroll
    for (int m = 0; m < 4; ++m) {
      const int row = wr * 64 + m * 16 + r16;
      ah[m] = *reinterpret_cast<const frag_ab*>(sAhi + row * 64 + slot * 8);
      al[m] = *reinterpret_cast<const frag_ab*>(sAlo + row * 64 + slot * 8);
    }
    #pragma unroll
    for (int n = 0; n < 4; ++n) {
      const int row = wc * 64 + n * 16 + r16;
      bh[n] = *reinterpret_cast<const frag_ab*>(sBhi + row * 64 + slot * 8);
      bl[n] = *reinterpret_cast<const frag_ab*>(sBlo + row * 64 + slot * 8);
    }
    #pragma unroll
    for (int m = 0; m < 4; ++m) {
      #pragma unroll
      for (int n = 0; n < 4; ++n) {
        acc[m][n] = __builtin_amdgcn_mfma_f32_16x16x32_bf16(ah[m], bh[n], acc[m][n], 0, 0, 0);
        acc[m][n] = __builtin_amdgcn_mfma_f32_16x16x32_bf16(ah[m], bl[n], acc[m][n], 0, 0, 0);
        acc[m][n] = __builtin_amdgcn_mfma_f32_16x16x32_bf16(al[m], bh[n], acc[m][n], 0, 0, 0);
      }
    }
  }

  float csq_[4];
  #pragma unroll
  for (int n = 0; n < 4; ++n) csq_[n] = sBsq[wc * 64 + n * 16 + r16];

  const size_t row0 = (size_t)mt * 128;
  const int col0 = nt * 128 + wc * 64;

  #pragma unroll
  for (int m = 0; m < 4; ++m) {
    #pragma unroll
    for (int r = 0; r < 4; ++r) {
      const int rl = wr * 64 + m * 16 + g * 4 + r;
      const float xsv = sAsq[rl];
      float* orow = out + (row0 + rl) * (size_t)NTOT + col0;
      #pragma unroll
      for (int n = 0; n < 4; ++n) {
        float l2 = fmaxf(xsv + csq_[n] - 2.0f * acc[m][n][r], 0.0f);
        orow[n * 16 + r16] = __expf(-GAMMA * l2);
      }
    }
  }
}

extern "C" void kernel_launch(void* const* d_in, const int* in_sizes, int n_in,
                              void* d_out, int out_size, void* d_ws, size_t ws_size,
                              hipStream_t stream) {
  (void)in_sizes; (void)n_in; (void)out_size;
  const float* x = (const float*)d_in[0];
  const float* centers = (const float*)d_in[1];
  float* out = (float*)d_out;

  if (ws_size >= WS_NEEDED && d_ws != nullptr) {
    char* ws = (char*)d_ws;
    ushort* xhi = (ushort*)(ws + WS_XHI);
    ushort* xlo = (ushort*)(ws + WS_XLO);
    ushort* chi = (ushort*)(ws + WS_CHI);
    ushort* clo = (ushort*)(ws + WS_CLO);
    float* xsq = (float*)(ws + WS_XSQ);
    float* csq = (float*)(ws + WS_CSQ);

    rbf_convert_kernel<<<(MTOT * 8) / 256, 256, 0, stream>>>(x, xhi, xlo, xsq);
    rbf_convert_kernel<<<(1024 * 8) / 256, 256, 0, stream>>>(centers, chi, clo, csq);
    rbf_gemm_kernel<<<(MTOT / 64) * (NTOT / 128), 256, 0, stream>>>(
        xhi, xlo, chi, clo, xsq, csq, out);
  } else {
    rbf_fallback_kernel<<<(MTOT / 128) * (NTOT / 128), 256, 0, stream>>>(x, centers, out);
  }
}